// Round 7
// baseline (243.005 us; speedup 1.0000x reference)
//
#include <hip/hip_runtime.h>
#include <math.h>

#define NEGV   -10000000000.0f
#define LOG2E  1.44269504088896340736f
#define LN2F   0.69314718055994530942f
#define SENT   0xAAAAAAAAu    // LDS sentinel; real published values never hit it

typedef float f4 __attribute__((ext_vector_type(4)));

constexpr int CS   = 16;          // diagonal steps per theta-staging chunk
constexpr int ROWS = 80;          // staged rows per wave-chunk (need 79)
constexpr int WL   = 17;          // LDS words per row (16 data + 1 pad)
constexpr int CHW  = ROWS * WL;   // words per chunk buffer (1360)
constexpr int GMAX = 256;         // boundary groups per wave (64 chunks * 4)

// One block per batch, 8 waves, ZERO barriers after init. Thread j owns DP
// column j+1; waves free-run. Boundary handoff is FINE-GRAINED: producer
// lane 63 publishes a 4-step group (one ds_write_b128) into a full-history,
// sentinel-initialized LDS buffer — data IS the flag (DS pipe is in-order
// per wave; dword writes are atomic, torn lines show sentinel). Consumer
// speculatively prefetches group gi+1 during group gi's 4-step compute and
// validates at use. This lets wave w+1 lag wave w by ~4 steps instead of a
// full 16-step chunk: all 8 waves run concurrently at chain rate.
__global__ __launch_bounds__(512, 1) void nw_kernel(
    const float* __restrict__ theta, const float* __restrict__ A,
    float* __restrict__ out, int N, int M)
{
    __shared__ float thS[8 * 2 * CHW];   // 87,040 B wave-private theta
    __shared__ f4    bndS[8 * GMAX];     // 32,768 B boundary history

    const int tid = threadIdx.x;
    const int w   = tid >> 6;
    const int l   = tid & 63;
    const int j   = tid;                 // owns column j+1
    const int b   = blockIdx.x;
    const int NW  = blockDim.x >> 6;

    {
        const float sf = __uint_as_float(SENT);
        const f4 sv = {sf, sf, sf, sf};
        for (int i = tid; i < 8 * GMAX; i += blockDim.x) bndS[i] = sv;
    }
    __syncthreads();                     // only barrier in the kernel

    const float a2 = A[b] * LOG2E;
    const float* __restrict__ thb = theta + (size_t)b * N * M;
    const int NM = N * M;

    const int T  = N + M - 1;
    const int KC = (T + CS - 1) / CS;
    const int wend = 64 * w + 63 + N - 1;
    const int ca = (64 * w) / CS;
    const int cb = min(KC - 1, wend / CS);
    // last producer group this wave will ever wait on (lane 0 active range)
    const int gmaxw = (64 * w + N - 2) >> 2;

    const int srow = l >> 4, sq = l & 15;
    const int lanebase = srow * (M - 1) + 64 * w + 63 + sq;
    const int wrbase0 = (w * 2 + 0) * CHW + srow * WL + sq;
    const int wrbase1 = (w * 2 + 1) * CHW + srow * WL + sq;
    const int rdbase0 = (w * 2 + 0) * CHW + (63 - l) * WL;
    const int rdbase1 = (w * 2 + 1) * CHW + (63 - l) * WL;

    auto stage_load = [&](int cn, float* stg) {
        const int rb = CS * cn - 64 * w - 63;
        if (rb >= 0 && rb + (ROWS - 1) <= N - 1) {
            const float* p = thb + (size_t)rb * M;
            #pragma unroll
            for (int it = 0; it < 20; ++it) { stg[it] = p[lanebase]; p += 4 * (M - 1); }
        } else {
            const int rbM = rb * M;
            #pragma unroll
            for (int it = 0; it < 20; ++it) {
                int off = rbM + lanebase + it * 4 * (M - 1);
                off = min(max(off, 0), NM - 1);
                stg[it] = thb[off];
            }
        }
    };
    auto stage_write = [&](int cn, const float* stg) {
        const int wb = (cn & 1) ? wrbase1 : wrbase0;
        #pragma unroll
        for (int it = 0; it < 20; ++it) thS[wb + it * 4 * WL] = stg[it] * LOG2E;
    };

    volatile float* bndV = (volatile float*)bndS;
    auto bnd_load = [&](int slot) -> f4 {
        f4 r;
        r.x = bndV[slot * 4 + 0];
        r.y = bndV[slot * 4 + 1];
        r.z = bndV[slot * 4 + 2];
        r.w = bndV[slot * 4 + 3];
        return r;
    };
    auto bad = [&](f4 v) -> bool {
        return ((__float_as_uint(v.x) == SENT) | (__float_as_uint(v.y) == SENT) |
                (__float_as_uint(v.z) == SENT) | (__float_as_uint(v.w) == SENT)) != 0;
    };

    float v_prev = NEGV;
    float v_diag = (j == 0) ? 0.0f : NEGV;   // V2[0][0]=0 seeds thread 0
    float bcarry = NEGV;

    // prologue: stage first chunk (same-wave DS in-order: no wait needed)
    {
        float s0[20];
        stage_load(ca, s0);
        stage_write(ca, s0);
        __asm__ volatile("" ::: "memory");
    }
    // bcarry for first step: element 3 of producer group 16w-1
    if (w > 0) {
        float u;
        do { u = bndV[(w * GMAX + 16 * w - 1) * 4 + 3]; }
        while (__float_as_uint(u) == SENT);
        bcarry = u;
    }
    // speculative prefetch of first boundary group
    f4 nxt;
    { const float sf = __uint_as_float(SENT); nxt = (f4){sf, sf, sf, sf}; }
    if (w > 0 && 16 * w <= gmaxw) nxt = bnd_load(w * GMAX + 16 * w);

    float stg[20];
    bool have = (ca + 1 <= cb);
    if (have) stage_load(ca + 1, stg);

    for (int c = ca; c <= cb; ++c) {
        const int rdb = (c & 1) ? rdbase1 : rdbase0;
        float th[16];
        #pragma unroll
        for (int k = 0; k < 16; ++k) th[k] = thS[rdb + k * (WL + 1)];

        const int tmj = CS * c - j;   // t - j at k = 0

        #pragma unroll
        for (int g = 0; g < 4; ++g) {
            const int gi = 4 * c + g;
            float bv0, bv1, bv2, bv3;
            if (w > 0 && gi <= gmaxw) {
                f4 cur = nxt;
                while (bad(cur)) cur = bnd_load(w * GMAX + gi);  // rare: fill only
                bv0 = cur.x; bv1 = cur.y; bv2 = cur.z; bv3 = cur.w;
                if (gi + 1 <= gmaxw) nxt = bnd_load(w * GMAX + gi + 1);
            } else {
                bv0 = bv1 = bv2 = bv3 = NEGV;
            }

            const float bks[4] = {bcarry, bv0, bv1, bv2};
            float r[4];
            #pragma unroll
            for (int kk = 0; kk < 4; ++kk) {
                const int k = 4 * g + kk;
                float vl = __int_as_float(__builtin_amdgcn_update_dpp(
                    __float_as_int(bks[kk]), __float_as_int(v_prev),
                    0x138 /* wave_shr:1 */, 0xF, 0xF, false));
                float x = a2 + v_prev;
                float z = a2 + vl;
                float m = fmaxf(fmaxf(x, v_diag), z);
                float s = __builtin_amdgcn_exp2f(x - m)
                        + __builtin_amdgcn_exp2f(v_diag - m)
                        + __builtin_amdgcn_exp2f(z - m);
                float v = th[k] + m + __builtin_amdgcn_logf(s);
                int dt = tmj + k;            // t - j; active iff 0 <= dt < N
                float vn = ((unsigned)dt < (unsigned)N) ? v
                                                        : (dt < 0 ? NEGV : v_prev);
                r[kk]  = vn;
                v_diag = vl;
                v_prev = vn;
            }
            bcarry = bv3;

            if (w < NW - 1 && l == 63)
                bndS[(w + 1) * GMAX + gi] = (f4){r[0], r[1], r[2], r[3]};
            __asm__ volatile("" ::: "memory");   // pin publish order (0-cost)
        }

        if (have) stage_write(c + 1, stg);
        have = (c + 2 <= cb);
        if (have) stage_load(c + 2, stg);
        __asm__ volatile("" ::: "memory");
    }

    if (j == M - 1) out[b] = v_prev * LN2F;   // V[N][M], back to ln domain
}

extern "C" void kernel_launch(void* const* d_in, const int* in_sizes, int n_in,
                              void* d_out, int out_size, void* d_ws, size_t ws_size,
                              hipStream_t stream) {
    const float* theta = (const float*)d_in[0];
    const float* A     = (const float*)d_in[1];
    float* out = (float*)d_out;

    const int B  = in_sizes[1];
    const int NM = in_sizes[0] / B;
    int N = 1;
    while (N * N < NM) N <<= 1;   // 512x512 expected
    const int M = NM / N;

    hipLaunchKernelGGL(nw_kernel, dim3(B), dim3(M), 0, stream,
                       theta, A, out, N, M);
}